// Round 1
// 2212.516 us; speedup vs baseline: 1.0510x; 1.0510x over previous
//
#include <hip/hip_runtime.h>
#include <hip/hip_bf16.h>

typedef __hip_bfloat16 bf16;
typedef __attribute__((ext_vector_type(8))) short short8;
typedef __attribute__((ext_vector_type(4))) float floatx4;
typedef __attribute__((ext_vector_type(16))) float floatx16;

#define D_MODEL 128
#define VOCAB   4096
#define N_LAYERS 4
#define D_FF    512
#define D_INNER 256
#define D_STATE 16
#define DT_RANK 8
#define BATCH   8
#define SEQ     4096
#define NTOK    (BATCH*SEQ)        // 32768
#define NCHUNK  16
#define CHUNK   256

__device__ __forceinline__ float bf2f(bf16 v) { return __bfloat162float(v); }
__device__ __forceinline__ bf16  f2bf(float v) { return __float2bfloat16(v); }

__device__ __forceinline__ void load_lds16(const void* g, void* l) {
  __builtin_amdgcn_global_load_lds(
      (const __attribute__((address_space(1))) unsigned int*)g,
      (__attribute__((address_space(3))) unsigned int*)l, 16, 0, 0);
}

__device__ __forceinline__ void store_out(float* p, float v) { *p = v; }
__device__ __forceinline__ void store_out(bf16* p, float v) { *p = f2bf(v); }

// ---------------------------------------------------------------------------
// Weight convert: fp32 row-major W[K][N] -> bf16 transposed (padded) Wt[N][K]
// Segments: W_in_t 4x[512][128] | W_xproj_t 4x[128][256] (pad 40->128) |
//           W_out_t 4x[128][256] | W1t [512][128] | W2t [4096][512]
// ---------------------------------------------------------------------------
#define WT_TOTAL 2686976
__global__ void convw_kernel(const float* __restrict__ W_in,
                             const float* __restrict__ W_xproj,
                             const float* __restrict__ W_out,
                             const float* __restrict__ W1,
                             const float* __restrict__ W2,
                             bf16* __restrict__ Wt) {
  for (int o = blockIdx.x * blockDim.x + threadIdx.x; o < WT_TOTAL;
       o += gridDim.x * blockDim.x) {
    float v;
    if (o < 262144) {
      int l = o >> 16, r = o & 65535, n = r >> 7, k = r & 127;
      v = W_in[l * 65536 + k * 512 + n];
    } else if (o < 393216) {
      int p = o - 262144, l = p >> 15, r = p & 32767, n = r >> 8, k = r & 255;
      v = (n < 40) ? W_xproj[l * 10240 + k * 40 + n] : 0.f;
    } else if (o < 524288) {
      int p = o - 393216, l = p >> 15, r = p & 32767, n = r >> 8, k = r & 255;
      v = W_out[l * 32768 + k * 128 + n];
    } else if (o < 589824) {
      int p = o - 524288, n = p >> 7, k = p & 127;
      v = W1[k * 512 + n];
    } else {
      int p = o - 589824, n = p >> 9, k = p & 511;
      v = W2[k * 4096 + n];
    }
    Wt[o] = f2bf(v);
  }
}

// ---------------------------------------------------------------------------
// Embedding gather: X[bl][128] = emb[tokens[bl]]
// ---------------------------------------------------------------------------
__global__ void embed_kernel(const int* __restrict__ tokens,
                             const float* __restrict__ emb,
                             float* __restrict__ X) {
  int idx = blockIdx.x * 256 + threadIdx.x;   // over 32768*32 float4s
  int bl = idx >> 5, c = idx & 31;
  int tok = tokens[bl];
  ((float4*)X)[(long)bl * 32 + c] = ((const float4*)emb)[(long)tok * 32 + c];
}

// ---------------------------------------------------------------------------
// LayerNorm over 128 + cast bf16. One wave per row, 4 rows per block.
// ---------------------------------------------------------------------------
__global__ __launch_bounds__(256) void ln_kernel(const float* __restrict__ X,
                                                 const float* __restrict__ w,
                                                 const float* __restrict__ b,
                                                 bf16* __restrict__ XN) {
  int wv = threadIdx.x >> 6, lane = threadIdx.x & 63;
  long row = (long)blockIdx.x * 4 + wv;
  const float* xp = X + row * 128;
  float2 v = *(const float2*)(xp + lane * 2);
  float s = v.x + v.y, q = v.x * v.x + v.y * v.y;
  #pragma unroll
  for (int o = 32; o; o >>= 1) {
    s += __shfl_xor(s, o, 64);
    q += __shfl_xor(q, o, 64);
  }
  float mu = s * (1.f / 128.f);
  float var = q * (1.f / 128.f) - mu * mu;
  float rs = rsqrtf(var + 1e-5f);
  int c = lane * 2;
  float o0 = (v.x - mu) * rs * w[c] + b[c];
  float o1 = (v.y - mu) * rs * w[c + 1] + b[c + 1];
  bf16* op = XN + row * 128 + c;
  op[0] = f2bf(o0);
  op[1] = f2bf(o1);
}

// ---------------------------------------------------------------------------
// Generic bf16 GEMM (legacy path, kept for N<=128 outputs):
// C[M][N] = A[M][K] @ Bt[N][K]^T  (+bias, +relu)
// 128x128 tile, BK=64, 4 waves of 64x64, mfma_f32_16x16x32_bf16.
// ---------------------------------------------------------------------------
template <typename OutT>
__global__ __launch_bounds__(256) void gemm_kernel(
    const bf16* __restrict__ A, const bf16* __restrict__ Bt,
    OutT* __restrict__ C, const float* __restrict__ bias,
    int K, int N, int relu) {
  __shared__ __align__(16) bf16 As[128 * 64];
  __shared__ __align__(16) bf16 Bs[128 * 64];
  const int tid = threadIdx.x;
  const int lane = tid & 63;
  const int wave = tid >> 6;
  const int m0 = blockIdx.x * 128;
  const int n0 = blockIdx.y * 128;
  const int wm = (wave >> 1) * 64;
  const int wn = (wave & 1) * 64;
  floatx4 acc[4][4] = {};

  const int lrow = lane >> 3;        // 0..7
  const int lcol = (lane & 7) * 8;   // bf16 col offset (16B granules)
  for (int k0 = 0; k0 < K; k0 += 64) {
    #pragma unroll
    for (int j = 0; j < 4; ++j) {
      int qq = wave * 4 + j;          // 0..15 -> rows qq*8..qq*8+7
      int row = qq * 8 + lrow;
      load_lds16(A + (long)(m0 + row) * K + k0 + lcol, &As[(qq * 8) * 64]);
      load_lds16(Bt + (long)(n0 + row) * K + k0 + lcol, &Bs[(qq * 8) * 64]);
    }
    __syncthreads();
    #pragma unroll
    for (int kk = 0; kk < 64; kk += 32) {
      short8 af[4], bfr[4];
      const int fr = lane & 15;
      const int fq = (lane >> 4) * 8 + kk;
      #pragma unroll
      for (int i = 0; i < 4; ++i) {
        af[i]  = *(const short8*)&As[(wm + i * 16 + fr) * 64 + fq];
        bfr[i] = *(const short8*)&Bs[(wn + i * 16 + fr) * 64 + fq];
      }
      #pragma unroll
      for (int mi = 0; mi < 4; ++mi)
        #pragma unroll
        for (int ni = 0; ni < 4; ++ni)
          acc[mi][ni] = __builtin_amdgcn_mfma_f32_16x16x32_bf16(
              af[mi], bfr[ni], acc[mi][ni], 0, 0, 0);
    }
    __syncthreads();
  }
  const int cr = (lane >> 4) * 4;   // row base within 16x16 frag
  const int cc = lane & 15;         // col within frag
  #pragma unroll
  for (int ni = 0; ni < 4; ++ni) {
    int col = n0 + wn + ni * 16 + cc;
    if (col >= N) continue;
    float bv = bias ? bias[col] : 0.f;
    #pragma unroll
    for (int mi = 0; mi < 4; ++mi) {
      #pragma unroll
      for (int r = 0; r < 4; ++r) {
        int row = m0 + wm + mi * 16 + cr + r;
        float v = acc[mi][ni][r] + bv;
        if (relu) v = fmaxf(v, 0.f);
        store_out(&C[(long)row * N + col], v);
      }
    }
  }
}

// ---------------------------------------------------------------------------
// Pipelined 256x256 GEMM (T1+T2+T3+T4+T5 stack), BK=32, 8 waves (2Mx4N),
// mfma_f32_32x32x16_bf16, static 64 KiB LDS double-buffer, counted vmcnt.
//
//  - per K-tile: 2 phases; each phase = {waitcnt vmcnt(N), s_barrier,
//    issue 1 prefetch round (A or B half), ds_read frags, 8 MFMA w/ setprio}.
//    Never vmcnt(0) in the loop.
//  - prefetch issue order per tile: J0=A-a{rows 0-63,128-191},
//    J1=B-a{0-63,128-191}, J2=B-b{64-127,192-255}, J3=A-b{64-127,192-255}.
//    phase0 reads rows [wm,wm+64) of A + all B -> needs J0,J1,J2 -> vmcnt(1)
//    phase1 reads rows [wm+64,wm+128) of A      -> needs J3       -> vmcnt(2)
//  - LDS granule swizzle g ^= (row&3) applied on the *global source* of
//    global_load_lds (dest stays linear) and on ds_read -> 2-way (free) banks.
//  - grid is 1-D, XCD-chunked: XCD x owns contiguous M-panels, bn fastest,
//    so the B panel stays resident in that XCD's L2.
//  - requires: M%256==0, N%256==0, K%32==0, grid=(M/256)*(N/256) %8==0.
// ---------------------------------------------------------------------------
template <typename OutT>
__global__ __launch_bounds__(512, 2) void gemm256_kernel(
    const bf16* __restrict__ A, const bf16* __restrict__ Bt,
    OutT* __restrict__ C, const float* __restrict__ bias,
    int K, int N, int ntiles, int relu) {
  __shared__ __align__(16) bf16 sA[2][256 * 32];
  __shared__ __align__(16) bf16 sB[2][256 * 32];
  const int tid  = threadIdx.x;
  const int lane = tid & 63;
  const int wave = tid >> 6;              // 0..7
  const int wm = (wave >> 2) << 7;        // 0 / 128
  const int wn = (wave & 3) << 6;         // 0,64,128,192

  // T1: bijective XCD-chunked swizzle (nwg % 8 == 0 by construction)
  const int nwg = gridDim.x;
  const int cpx = nwg >> 3;
  const int id  = ((int)blockIdx.x & 7) * cpx + ((int)blockIdx.x >> 3);
  const int bm = id / ntiles, bn = id - bm * ntiles;
  const long m0 = (long)bm << 8;
  const long n0 = (long)bn << 8;

  const bf16* Ab = A + m0 * K;
  const bf16* Bb = Bt + n0 * K;

  // staging lane constants: 1 KiB per wave-instruction = 16 rows x 64 B;
  // lane l -> row srow=l>>2, phys granule l&3, pre-swizzled global granule.
  const int srow = lane >> 2;                         // 0..15
  const int sgl  = (((lane & 3) ^ (srow & 3)) << 3);  // bf16 elems
  const int NT = K >> 5;

  const int wh16  = (wave & 3) << 4;
  const int aoff0 = (wave < 4) ? wh16 : (128 + wh16); // round a slab start
  const int aoff1 = aoff0 + 64;                       // round b slab start

#define STAGE(src, dst, r0, k0)                                           \
  load_lds16((src) + (long)((r0) + srow) * K + (k0) + sgl, (dst) + (r0) * 32)

  // prologue: tile 0 -> buf 0   (J0, J1, J2, J3)
  STAGE(Ab, sA[0], aoff0, 0);
  STAGE(Bb, sB[0], aoff0, 0);
  STAGE(Bb, sB[0], aoff1, 0);
  STAGE(Ab, sA[0], aoff1, 0);

  floatx16 acc[4][2] = {};
  const int frow = lane & 31;   // A row / B row (=out col) within 32-frag
  const int fg   = lane >> 5;   // k-granule select

  for (int t = 0; t < NT; ++t) {
    const int cur = t & 1, nxt = cur ^ 1;
    const int kn = (t + 1 < NT) ? ((t + 1) << 5) : 0;  // dummy reload on last
    const bf16* cA = sA[cur];
    const bf16* cB = sB[cur];

    // ---------------- phase 0: out rows [wm, wm+64) ----------------
    asm volatile("s_waitcnt vmcnt(1)" ::: "memory");   // J0,J1,J2 of tile t
    asm volatile("s_barrier" ::: "memory");
    STAGE(Ab, sA[nxt], aoff0, kn);                     // J0(t+1)
    STAGE(Bb, sB[nxt], aoff0, kn);                     // J1(t+1)
    short8 a0[2][2], b0[2][2];
    #pragma unroll
    for (int mi = 0; mi < 2; ++mi)
      #pragma unroll
      for (int kk = 0; kk < 2; ++kk) {
        int r = wm + mi * 32 + frow;
        int g = kk * 2 + fg;
        a0[mi][kk] = *(const short8*)&cA[r * 32 + ((g ^ (r & 3)) << 3)];
      }
    #pragma unroll
    for (int ni = 0; ni < 2; ++ni)
      #pragma unroll
      for (int kk = 0; kk < 2; ++kk) {
        int r = wn + ni * 32 + frow;
        int g = kk * 2 + fg;
        b0[ni][kk] = *(const short8*)&cB[r * 32 + ((g ^ (r & 3)) << 3)];
      }
    __builtin_amdgcn_s_setprio(1);
    #pragma unroll
    for (int mi = 0; mi < 2; ++mi)
      #pragma unroll
      for (int ni = 0; ni < 2; ++ni)
        #pragma unroll
        for (int kk = 0; kk < 2; ++kk)
          acc[mi][ni] = __builtin_amdgcn_mfma_f32_32x32x16_bf16(
              a0[mi][kk], b0[ni][kk], acc[mi][ni], 0, 0, 0);
    __builtin_amdgcn_s_setprio(0);

    // ---------------- phase 1: out rows [wm+64, wm+128) ----------------
    asm volatile("s_waitcnt vmcnt(2)" ::: "memory");   // J3 of tile t
    asm volatile("s_barrier" ::: "memory");
    STAGE(Bb, sB[nxt], aoff1, kn);                     // J2(t+1)
    STAGE(Ab, sA[nxt], aoff1, kn);                     // J3(t+1)
    short8 a1[2][2];
    #pragma unroll
    for (int mi = 0; mi < 2; ++mi)
      #pragma unroll
      for (int kk = 0; kk < 2; ++kk) {
        int r = wm + 64 + mi * 32 + frow;
        int g = kk * 2 + fg;
        a1[mi][kk] = *(const short8*)&cA[r * 32 + ((g ^ (r & 3)) << 3)];
      }
    __builtin_amdgcn_s_setprio(1);
    #pragma unroll
    for (int mi = 0; mi < 2; ++mi)
      #pragma unroll
      for (int ni = 0; ni < 2; ++ni)
        #pragma unroll
        for (int kk = 0; kk < 2; ++kk)
          acc[2 + mi][ni] = __builtin_amdgcn_mfma_f32_32x32x16_bf16(
              a1[mi][kk], b0[ni][kk], acc[2 + mi][ni], 0, 0, 0);
    __builtin_amdgcn_s_setprio(0);
  }
#undef STAGE

  // epilogue: 32x32 C frag: col = lane&31, row = (r&3) + 8*(r>>2) + 4*(lane>>5)
  // -> each reg's wave-store is 2 rows x 128 B contiguous.
  #pragma unroll
  for (int mi = 0; mi < 4; ++mi)
    #pragma unroll
    for (int ni = 0; ni < 2; ++ni) {
      long col = n0 + wn + ni * 32 + frow;
      float bv = bias ? bias[col] : 0.f;
      #pragma unroll
      for (int r = 0; r < 16; ++r) {
        long row = m0 + wm + mi * 32 + (r & 3) + ((r >> 2) << 3) + (fg << 2);
        float v = acc[mi][ni][r] + bv;
        if (relu) v = fmaxf(v, 0.f);
        store_out(&C[row * N + col], v);
      }
    }
}

// ---------------------------------------------------------------------------
// Causal depthwise conv(4) + SiLU -> U(bf16); also silu(z) -> G(bf16)
// block=256 (d), grid=32768 (bl)
// ---------------------------------------------------------------------------
__global__ __launch_bounds__(256) void conv_silu_kernel(
    const float* __restrict__ XZ, const float* __restrict__ conv_w,
    const float* __restrict__ conv_b, bf16* __restrict__ U,
    bf16* __restrict__ G) {
  int d = threadIdx.x;
  long bl = blockIdx.x;
  int t = (int)(bl & (SEQ - 1));
  float w0 = conv_w[d * 4 + 0], w1 = conv_w[d * 4 + 1];
  float w2 = conv_w[d * 4 + 2], w3 = conv_w[d * 4 + 3];
  const float* xp = XZ + bl * 512 + d;
  float acc = conv_b[d] + w3 * xp[0];
  if (t >= 1) acc += w2 * xp[-512];
  if (t >= 2) acc += w1 * xp[-1024];
  if (t >= 3) acc += w0 * xp[-1536];
  float su = acc / (1.f + __expf(-acc));
  float z = xp[256];
  float g = z / (1.f + __expf(-z));
  U[bl * 256 + d] = f2bf(su);
  G[bl * 256 + d] = f2bf(g);
}

// ---------------------------------------------------------------------------
// dt = softplus(dt_r @ W_dt + b_dt). block=256 (d), grid=32768 (bl)
// ---------------------------------------------------------------------------
__global__ __launch_bounds__(256) void dtprep_kernel(
    const float* __restrict__ DBC, const float* __restrict__ W_dt,
    const float* __restrict__ b_dt, float* __restrict__ DTo) {
  __shared__ float r8[8];
  int d = threadIdx.x;
  long bl = blockIdx.x;
  if (d < 8) r8[d] = DBC[bl * 40 + d];
  __syncthreads();
  float acc = b_dt[d];
  #pragma unroll
  for (int r = 0; r < 8; ++r) acc = fmaf(r8[r], W_dt[r * 256 + d], acc);
  float dt = (acc > 15.f) ? acc : log1pf(__expf(acc));
  DTo[bl * 256 + d] = dt;
}

// ---------------------------------------------------------------------------
// Chunked scan pass 1: per (b,d,s,chunk) run from h=0, record P=prod(a), S=h.
// block: 256 thr = 16 d x 16 s. grid = (16 dgroup, 16 chunk, 8 b)
// ---------------------------------------------------------------------------
__global__ __launch_bounds__(256) void scan_pass1_kernel(
    const float* __restrict__ DT, const bf16* __restrict__ U,
    const float* __restrict__ DBC, const float* __restrict__ A_log,
    float* __restrict__ CSP, float* __restrict__ CSS) {
  int s = threadIdx.x & 15, dd = threadIdx.x >> 4;
  int d = blockIdx.x * 16 + dd;
  int c = blockIdx.y, b = blockIdx.z;
  float A2 = -__expf(A_log[d * 16 + s]) * 1.44269504088896f;
  long t0 = (long)b * SEQ + (long)c * CHUNK;
  const float* dtp = DT + t0 * 256 + d;
  const bf16* up = U + t0 * 256 + d;
  const float* bp = DBC + t0 * 40 + 8 + s;
  float h = 0.f, P = 1.f;
  #pragma unroll 4
  for (int t = 0; t < CHUNK; ++t) {
    float dt = *dtp;
    float u = bf2f(*up);
    float Bv = *bp;
    float a = __builtin_amdgcn_exp2f(dt * A2);
    h = fmaf(a, h, dt * u * Bv);
    P *= a;
    dtp += 256; up += 256; bp += 40;
  }
  int idx = (b * 16 + c) * 4096 + d * 16 + s;
  CSP[idx] = P;
  CSS[idx] = h;
}

// ---------------------------------------------------------------------------
// Chain chunk states: hinit[c] = S[c-1] + P[c-1]*hinit[c-1]. 32768 threads.
// ---------------------------------------------------------------------------
__global__ __launch_bounds__(256) void scan_combine_kernel(
    const float* __restrict__ P, const float* __restrict__ S,
    float* __restrict__ HI) {
  int id = blockIdx.x * 256 + threadIdx.x;  // (b, d*16+s)
  int b = id >> 12, ds = id & 4095;
  float h = 0.f;
  #pragma unroll
  for (int c = 0; c < NCHUNK; ++c) {
    int idx = ((b * 16 + c) << 12) + ds;
    HI[idx] = h;
    h = S[idx] + P[idx] * h;
  }
}

// ---------------------------------------------------------------------------
// Chunked scan pass 2: replay with h_init, reduce y over s, fuse skip+gate.
// Y (bf16) = (y + u*D_skip) * silu(z)
// ---------------------------------------------------------------------------
__global__ __launch_bounds__(256) void scan_pass2_kernel(
    const float* __restrict__ DT, const bf16* __restrict__ U,
    const float* __restrict__ DBC, const bf16* __restrict__ G,
    const float* __restrict__ HI, const float* __restrict__ A_log,
    const float* __restrict__ D_skip, bf16* __restrict__ Y) {
  int s = threadIdx.x & 15, dd = threadIdx.x >> 4;
  int d = blockIdx.x * 16 + dd;
  int c = blockIdx.y, b = blockIdx.z;
  float A2 = -__expf(A_log[d * 16 + s]) * 1.44269504088896f;
  float Dv = D_skip[d];
  long t0 = (long)b * SEQ + (long)c * CHUNK;
  const float* dtp = DT + t0 * 256 + d;
  const bf16* up = U + t0 * 256 + d;
  const bf16* gp = G + t0 * 256 + d;
  const float* bp = DBC + t0 * 40 + 8 + s;
  bf16* yp = Y + t0 * 256 + d;
  int idx = (b * 16 + c) * 4096 + d * 16 + s;
  float h = HI[idx];
  #pragma unroll 4
  for (int t = 0; t < CHUNK; ++t) {
    float dt = *dtp;
    float u = bf2f(*up);
    float Bv = *bp;
    float Cv = bp[16];
    float a = __builtin_amdgcn_exp2f(dt * A2);
    h = fmaf(a, h, dt * u * Bv);
    float p = h * Cv;
    p += __shfl_xor(p, 8, 16);
    p += __shfl_xor(p, 4, 16);
    p += __shfl_xor(p, 2, 16);
    p += __shfl_xor(p, 1, 16);
    if (s == 0) {
      float g = bf2f(*gp);
      *yp = f2bf((p + u * Dv) * g);
    }
    dtp += 256; up += 256; gp += 256; bp += 40; yp += 256;
  }
}

// ---------------------------------------------------------------------------
// kernel_launch
// ---------------------------------------------------------------------------
extern "C" void kernel_launch(void* const* d_in, const int* in_sizes, int n_in,
                              void* d_out, int out_size, void* d_ws,
                              size_t ws_size, hipStream_t stream) {
  const int*   tokens  = (const int*)d_in[0];
  const float* emb     = (const float*)d_in[1];
  const float* ln_w    = (const float*)d_in[2];
  const float* ln_b    = (const float*)d_in[3];
  const float* W_in    = (const float*)d_in[4];
  const float* conv_w  = (const float*)d_in[5];
  const float* conv_b  = (const float*)d_in[6];
  const float* W_xproj = (const float*)d_in[7];
  const float* W_dt    = (const float*)d_in[8];
  const float* b_dt    = (const float*)d_in[9];
  const float* A_log   = (const float*)d_in[10];
  const float* D_skip  = (const float*)d_in[11];
  const float* W_out   = (const float*)d_in[12];
  const float* W1      = (const float*)d_in[13];
  const float* b1      = (const float*)d_in[14];
  const float* W2      = (const float*)d_in[15];
  const float* b2      = (const float*)d_in[16];

  char* ws = (char*)d_ws;
  float* X    = (float*)(ws + 0);              // 32768*128 f32   16.8MB
  float* XZ   = (float*)(ws + 16777216);       // 32768*512 f32   67.1MB
  bf16*  XN   = (bf16*) (ws + 83886080);       // 32768*128 bf16   8.4MB (reused as XBF)
  bf16*  U    = (bf16*) (ws + 92274688);       // 32768*256 bf16  16.8MB
  bf16*  G    = (bf16*) (ws + 109051904);      // 32768*256 bf16  16.8MB
  float* DBC  = (float*)(ws + 125829120);      // 32768*40  f32    5.2MB
  float* DT   = (float*)(ws + 131072000);      // 32768*256 f32   33.6MB
  bf16*  Y    = (bf16*) (ws + 164626432);      // 32768*256 bf16  16.8MB
  float* CSP  = (float*)(ws + 181403648);      // 524288 f32       2.1MB
  float* CSS  = (float*)(ws + 183500800);      // 524288 f32       2.1MB
  float* HI   = (float*)(ws + 185597952);      // 524288 f32       2.1MB
  bf16*  Wt   = (bf16*) (ws + 187695104);      // 2686976 bf16     5.4MB
  bf16*  H    = (bf16*) XZ;                    // overlay: 32768*512 bf16 (XZ dead by then)
  bf16*  XBF  = XN;                            // overlay: written at end of layer 3

  bf16* Wt_in  = Wt;              // 4 x [512][128]
  bf16* Wt_xp  = Wt + 262144;     // 4 x [128][256] (rows 40..127 zero)
  bf16* Wt_out = Wt + 393216;     // 4 x [128][256]
  bf16* Wt_1   = Wt + 524288;     // [512][128]
  bf16* Wt_2   = Wt + 589824;     // [4096][512]

  convw_kernel<<<2048, 256, 0, stream>>>(W_in, W_xproj, W_out, W1, W2, Wt);
  embed_kernel<<<4096, 256, 0, stream>>>(tokens, emb, X);

  for (int i = 0; i < N_LAYERS; ++i) {
    ln_kernel<<<8192, 256, 0, stream>>>(X, ln_w + i * 128, ln_b + i * 128, XN);
    // M=32768 (128 tiles) x N=512 (2 tiles) -> 256 blocks
    gemm256_kernel<float><<<256, 512, 0, stream>>>(
        XN, Wt_in + i * 65536, XZ, nullptr, 128, 512, 2, 0);
    conv_silu_kernel<<<32768, 256, 0, stream>>>(
        XZ, conv_w + i * 1024, conv_b + i * 256, U, G);
    gemm_kernel<float><<<dim3(256, 1), 256, 0, stream>>>(
        U, Wt_xp + i * 32768, DBC, nullptr, 256, 40, 0);
    dtprep_kernel<<<32768, 256, 0, stream>>>(
        DBC, W_dt + i * 2048, b_dt + i * 256, DT);
    scan_pass1_kernel<<<dim3(16, 16, 8), 256, 0, stream>>>(
        DT, U, DBC, A_log + i * 4096, CSP, CSS);
    scan_combine_kernel<<<128, 256, 0, stream>>>(CSP, CSS, HI);
    scan_pass2_kernel<<<dim3(16, 16, 8), 256, 0, stream>>>(
        DT, U, DBC, G, HI, A_log + i * 4096, D_skip + i * 256, Y);
    if (i < N_LAYERS - 1) {
      gemm_kernel<float><<<dim3(256, 1), 256, 0, stream>>>(
          Y, Wt_out + i * 32768, X, nullptr, 256, 128, 0);
    } else {
      gemm_kernel<bf16><<<dim3(256, 1), 256, 0, stream>>>(
          Y, Wt_out + i * 32768, XBF, nullptr, 256, 128, 0);
    }
  }

  // MLP head: H = relu(XBF @ W1 + b1) in bf16, then out = H @ W2 + b2 (fp32)
  // M=32768 x N=512 -> 256 blocks
  gemm256_kernel<bf16><<<256, 512, 0, stream>>>(
      XBF, Wt_1, H, b1, 128, 512, 2, 1);
  // M=32768 (128 tiles) x N=4096 (16 tiles) -> 2048 blocks
  gemm256_kernel<float><<<2048, 512, 0, stream>>>(
      H, Wt_2, (float*)d_out, b2, 512, 4096, 16, 0);
}

// Round 2
// 2192.406 us; speedup vs baseline: 1.0606x; 1.0092x over previous
//
#include <hip/hip_runtime.h>
#include <hip/hip_bf16.h>

typedef __hip_bfloat16 bf16;
typedef __attribute__((ext_vector_type(8))) short short8;
typedef __attribute__((ext_vector_type(4))) float floatx4;
typedef __attribute__((ext_vector_type(16))) float floatx16;

#define D_MODEL 128
#define VOCAB   4096
#define N_LAYERS 4
#define D_FF    512
#define D_INNER 256
#define D_STATE 16
#define DT_RANK 8
#define BATCH   8
#define SEQ     4096
#define NTOK    (BATCH*SEQ)        // 32768
#define NCHUNK  16
#define CHUNK   256

__device__ __forceinline__ float bf2f(bf16 v) { return __bfloat162float(v); }
__device__ __forceinline__ bf16  f2bf(float v) { return __float2bfloat16(v); }

__device__ __forceinline__ void load_lds16(const void* g, void* l) {
  __builtin_amdgcn_global_load_lds(
      (const __attribute__((address_space(1))) unsigned int*)g,
      (__attribute__((address_space(3))) unsigned int*)l, 16, 0, 0);
}

__device__ __forceinline__ void store_out(float* p, float v) { *p = v; }
__device__ __forceinline__ void store_out(bf16* p, float v) { *p = f2bf(v); }

// ---------------------------------------------------------------------------
// Weight convert: fp32 row-major W[K][N] -> bf16 transposed (padded) Wt[N][K]
// Segments: W_in_t 4x[512][128] | W_xproj_t 4x[128][256] (pad 40->128) |
//           W_out_t 4x[128][256] | W1t [512][128] | W2t [4096][512]
// ---------------------------------------------------------------------------
#define WT_TOTAL 2686976
__global__ void convw_kernel(const float* __restrict__ W_in,
                             const float* __restrict__ W_xproj,
                             const float* __restrict__ W_out,
                             const float* __restrict__ W1,
                             const float* __restrict__ W2,
                             bf16* __restrict__ Wt) {
  for (int o = blockIdx.x * blockDim.x + threadIdx.x; o < WT_TOTAL;
       o += gridDim.x * blockDim.x) {
    float v;
    if (o < 262144) {
      int l = o >> 16, r = o & 65535, n = r >> 7, k = r & 127;
      v = W_in[l * 65536 + k * 512 + n];
    } else if (o < 393216) {
      int p = o - 262144, l = p >> 15, r = p & 32767, n = r >> 8, k = r & 255;
      v = (n < 40) ? W_xproj[l * 10240 + k * 40 + n] : 0.f;
    } else if (o < 524288) {
      int p = o - 393216, l = p >> 15, r = p & 32767, n = r >> 8, k = r & 255;
      v = W_out[l * 32768 + k * 128 + n];
    } else if (o < 589824) {
      int p = o - 524288, n = p >> 7, k = p & 127;
      v = W1[k * 512 + n];
    } else {
      int p = o - 589824, n = p >> 9, k = p & 511;
      v = W2[k * 4096 + n];
    }
    Wt[o] = f2bf(v);
  }
}

// ---------------------------------------------------------------------------
// Fused embedding gather + LayerNorm (layer 0) -> XN bf16.
// One wave per row, 4 rows per block. emb is 2MB -> L2-resident.
// ---------------------------------------------------------------------------
__global__ __launch_bounds__(256) void embln_kernel(
    const int* __restrict__ tokens, const float* __restrict__ emb,
    const float* __restrict__ w, const float* __restrict__ b,
    bf16* __restrict__ XN) {
  int wv = threadIdx.x >> 6, lane = threadIdx.x & 63;
  long row = (long)blockIdx.x * 4 + wv;
  int tok = tokens[row];
  const float* xp = emb + (long)tok * 128;
  float2 v = *(const float2*)(xp + lane * 2);
  float s = v.x + v.y, q = v.x * v.x + v.y * v.y;
  #pragma unroll
  for (int o = 32; o; o >>= 1) {
    s += __shfl_xor(s, o, 64);
    q += __shfl_xor(q, o, 64);
  }
  float mu = s * (1.f / 128.f);
  float var = q * (1.f / 128.f) - mu * mu;
  float rs = rsqrtf(var + 1e-5f);
  int c = lane * 2;
  float o0 = (v.x - mu) * rs * w[c] + b[c];
  float o1 = (v.y - mu) * rs * w[c + 1] + b[c + 1];
  bf16* op = XN + row * 128 + c;
  op[0] = f2bf(o0);
  op[1] = f2bf(o1);
}

// ---------------------------------------------------------------------------
// Legacy bf16 GEMM for narrow outputs: C[M][N] = A[M][K] @ Bt[N][K]^T
// 128x128 tile, BK=64, 4 waves of 64x64, mfma_f32_16x16x32_bf16.
// Granule XOR-swizzle (g ^= row&7) on staged source + frag read: 16-way ->
// 8-way bank conflicts (128B rows alias all 32 banks otherwise).
// EPI: 0 = plain store, 2 = fused LayerNorm over N=128 cols (OutT=bf16).
// ---------------------------------------------------------------------------
template <typename OutT, int EPI>
__global__ __launch_bounds__(256) void gemm_kernel(
    const bf16* __restrict__ A, const bf16* __restrict__ Bt,
    OutT* __restrict__ C, const float* __restrict__ lnw,
    const float* __restrict__ lnb, int K, int N) {
  __shared__ __align__(16) bf16 As[128 * 64];
  __shared__ __align__(16) bf16 Bs[128 * 64];
  const int tid = threadIdx.x;
  const int lane = tid & 63;
  const int wave = tid >> 6;
  const int m0 = blockIdx.x * 128;
  const int n0 = blockIdx.y * 128;
  const int wm = (wave >> 1) * 64;
  const int wn = (wave & 1) * 64;
  floatx4 acc[4][4] = {};

  const int lrow = lane >> 3;                      // 0..7 row in 8-row slab
  const int lcol = ((lane & 7) ^ lrow) * 8;        // pre-swizzled src granule
  for (int k0 = 0; k0 < K; k0 += 64) {
    #pragma unroll
    for (int j = 0; j < 4; ++j) {
      int qq = wave * 4 + j;          // 0..15 -> rows qq*8..qq*8+7
      int row = qq * 8 + lrow;
      load_lds16(A + (long)(m0 + row) * K + k0 + lcol, &As[(qq * 8) * 64]);
      load_lds16(Bt + (long)(n0 + row) * K + k0 + lcol, &Bs[(qq * 8) * 64]);
    }
    __syncthreads();
    #pragma unroll
    for (int kk = 0; kk < 64; kk += 32) {
      short8 af[4], bfr[4];
      const int fr = lane & 15;
      const int q  = (lane >> 4) + (kk >> 3);      // logical granule
      #pragma unroll
      for (int i = 0; i < 4; ++i) {
        int ra = wm + i * 16 + fr;
        int rb = wn + i * 16 + fr;
        af[i]  = *(const short8*)&As[ra * 64 + ((q ^ (ra & 7)) << 3)];
        bfr[i] = *(const short8*)&Bs[rb * 64 + ((q ^ (rb & 7)) << 3)];
      }
      #pragma unroll
      for (int mi = 0; mi < 4; ++mi)
        #pragma unroll
        for (int ni = 0; ni < 4; ++ni)
          acc[mi][ni] = __builtin_amdgcn_mfma_f32_16x16x32_bf16(
              af[mi], bfr[ni], acc[mi][ni], 0, 0, 0);
    }
    __syncthreads();
  }
  const int cr = (lane >> 4) * 4;   // row base within 16x16 frag
  const int cc = lane & 15;         // col within frag

  if (EPI == 2) {
    // Fused LayerNorm: rows of this 128-col tile are complete here.
    // Per-thread partials over its 4 ni cols, shfl-reduce over cc (16 lanes),
    // cross-wave (wn 0/64) combine via LDS overlay on As.
    float* lnS = (float*)As;        // [128][2]
    float* lnQ = lnS + 256;         // [128][2]
    #pragma unroll
    for (int mi = 0; mi < 4; ++mi)
      #pragma unroll
      for (int r = 0; r < 4; ++r) {
        float s = 0.f, qs = 0.f;
        #pragma unroll
        for (int ni = 0; ni < 4; ++ni) {
          float v = acc[mi][ni][r];
          s += v; qs += v * v;
        }
        #pragma unroll
        for (int o = 1; o < 16; o <<= 1) {
          s  += __shfl_xor(s, o, 64);
          qs += __shfl_xor(qs, o, 64);
        }
        if (cc == 0) {
          int row = wm + mi * 16 + cr + r;
          lnS[row * 2 + (wave & 1)] = s;
          lnQ[row * 2 + (wave & 1)] = qs;
        }
      }
    __syncthreads();
    #pragma unroll
    for (int mi = 0; mi < 4; ++mi)
      #pragma unroll
      for (int r = 0; r < 4; ++r) {
        int row = wm + mi * 16 + cr + r;
        float tot  = lnS[row * 2] + lnS[row * 2 + 1];
        float totq = lnQ[row * 2] + lnQ[row * 2 + 1];
        float mu = tot * (1.f / 128.f);
        float var = totq * (1.f / 128.f) - mu * mu;
        float rs = rsqrtf(var + 1e-5f);
        #pragma unroll
        for (int ni = 0; ni < 4; ++ni) {
          int col = wn + ni * 16 + cc;
          float v = (acc[mi][ni][r] - mu) * rs * lnw[col] + lnb[col];
          store_out(&C[(long)(m0 + row) * 128 + col], v);
        }
      }
  } else {
    #pragma unroll
    for (int ni = 0; ni < 4; ++ni) {
      int col = n0 + wn + ni * 16 + cc;
      if (col >= N) continue;
      #pragma unroll
      for (int mi = 0; mi < 4; ++mi) {
        #pragma unroll
        for (int r = 0; r < 4; ++r) {
          int row = m0 + wm + mi * 16 + cr + r;
          store_out(&C[(long)row * N + col], acc[mi][ni][r]);
        }
      }
    }
  }
}

// ---------------------------------------------------------------------------
// Pipelined 256x256 GEMM (T1+T2+T3+T4+T5 stack), BK=32, 8 waves (2Mx4N),
// mfma_f32_32x32x16_bf16, static 64 KiB LDS double-buffer, counted vmcnt.
// ---------------------------------------------------------------------------
template <typename OutT>
__global__ __launch_bounds__(512, 2) void gemm256_kernel(
    const bf16* __restrict__ A, const bf16* __restrict__ Bt,
    OutT* __restrict__ C, const float* __restrict__ bias,
    int K, int N, int ntiles, int relu) {
  __shared__ __align__(16) bf16 sA[2][256 * 32];
  __shared__ __align__(16) bf16 sB[2][256 * 32];
  const int tid  = threadIdx.x;
  const int lane = tid & 63;
  const int wave = tid >> 6;              // 0..7
  const int wm = (wave >> 2) << 7;        // 0 / 128
  const int wn = (wave & 3) << 6;         // 0,64,128,192

  // T1: bijective XCD-chunked swizzle (nwg % 8 == 0 by construction)
  const int nwg = gridDim.x;
  const int cpx = nwg >> 3;
  const int id  = ((int)blockIdx.x & 7) * cpx + ((int)blockIdx.x >> 3);
  const int bm = id / ntiles, bn = id - bm * ntiles;
  const long m0 = (long)bm << 8;
  const long n0 = (long)bn << 8;

  const bf16* Ab = A + m0 * K;
  const bf16* Bb = Bt + n0 * K;

  const int srow = lane >> 2;                         // 0..15
  const int sgl  = (((lane & 3) ^ (srow & 3)) << 3);  // bf16 elems
  const int NT = K >> 5;

  const int wh16  = (wave & 3) << 4;
  const int aoff0 = (wave < 4) ? wh16 : (128 + wh16); // round a slab start
  const int aoff1 = aoff0 + 64;                       // round b slab start

#define STAGE(src, dst, r0, k0)                                           \
  load_lds16((src) + (long)((r0) + srow) * K + (k0) + sgl, (dst) + (r0) * 32)

  // prologue: tile 0 -> buf 0   (J0, J1, J2, J3)
  STAGE(Ab, sA[0], aoff0, 0);
  STAGE(Bb, sB[0], aoff0, 0);
  STAGE(Bb, sB[0], aoff1, 0);
  STAGE(Ab, sA[0], aoff1, 0);

  floatx16 acc[4][2] = {};
  const int frow = lane & 31;   // A row / B row (=out col) within 32-frag
  const int fg   = lane >> 5;   // k-granule select

  for (int t = 0; t < NT; ++t) {
    const int cur = t & 1, nxt = cur ^ 1;
    const int kn = (t + 1 < NT) ? ((t + 1) << 5) : 0;  // dummy reload on last
    const bf16* cA = sA[cur];
    const bf16* cB = sB[cur];

    // ---------------- phase 0: out rows [wm, wm+64) ----------------
    asm volatile("s_waitcnt vmcnt(1)" ::: "memory");   // J0,J1,J2 of tile t
    asm volatile("s_barrier" ::: "memory");
    STAGE(Ab, sA[nxt], aoff0, kn);                     // J0(t+1)
    STAGE(Bb, sB[nxt], aoff0, kn);                     // J1(t+1)
    short8 a0[2][2], b0[2][2];
    #pragma unroll
    for (int mi = 0; mi < 2; ++mi)
      #pragma unroll
      for (int kk = 0; kk < 2; ++kk) {
        int r = wm + mi * 32 + frow;
        int g = kk * 2 + fg;
        a0[mi][kk] = *(const short8*)&cA[r * 32 + ((g ^ (r & 3)) << 3)];
      }
    #pragma unroll
    for (int ni = 0; ni < 2; ++ni)
      #pragma unroll
      for (int kk = 0; kk < 2; ++kk) {
        int r = wn + ni * 32 + frow;
        int g = kk * 2 + fg;
        b0[ni][kk] = *(const short8*)&cB[r * 32 + ((g ^ (r & 3)) << 3)];
      }
    __builtin_amdgcn_s_setprio(1);
    #pragma unroll
    for (int mi = 0; mi < 2; ++mi)
      #pragma unroll
      for (int ni = 0; ni < 2; ++ni)
        #pragma unroll
        for (int kk = 0; kk < 2; ++kk)
          acc[mi][ni] = __builtin_amdgcn_mfma_f32_32x32x16_bf16(
              a0[mi][kk], b0[ni][kk], acc[mi][ni], 0, 0, 0);
    __builtin_amdgcn_s_setprio(0);

    // ---------------- phase 1: out rows [wm+64, wm+128) ----------------
    asm volatile("s_waitcnt vmcnt(2)" ::: "memory");   // J3 of tile t
    asm volatile("s_barrier" ::: "memory");
    STAGE(Bb, sB[nxt], aoff1, kn);                     // J2(t+1)
    STAGE(Ab, sA[nxt], aoff1, kn);                     // J3(t+1)
    short8 a1[2][2];
    #pragma unroll
    for (int mi = 0; mi < 2; ++mi)
      #pragma unroll
      for (int kk = 0; kk < 2; ++kk) {
        int r = wm + 64 + mi * 32 + frow;
        int g = kk * 2 + fg;
        a1[mi][kk] = *(const short8*)&cA[r * 32 + ((g ^ (r & 3)) << 3)];
      }
    __builtin_amdgcn_s_setprio(1);
    #pragma unroll
    for (int mi = 0; mi < 2; ++mi)
      #pragma unroll
      for (int ni = 0; ni < 2; ++ni)
        #pragma unroll
        for (int kk = 0; kk < 2; ++kk)
          acc[2 + mi][ni] = __builtin_amdgcn_mfma_f32_32x32x16_bf16(
              a1[mi][kk], b0[ni][kk], acc[2 + mi][ni], 0, 0, 0);
    __builtin_amdgcn_s_setprio(0);
  }
#undef STAGE

  // epilogue: 32x32 C frag: col = lane&31, row = (r&3) + 8*(r>>2) + 4*(lane>>5)
  #pragma unroll
  for (int mi = 0; mi < 4; ++mi)
    #pragma unroll
    for (int ni = 0; ni < 2; ++ni) {
      long col = n0 + wn + ni * 32 + frow;
      float bv = bias ? bias[col] : 0.f;
      #pragma unroll
      for (int r = 0; r < 16; ++r) {
        long row = m0 + wm + mi * 32 + (r & 3) + ((r >> 2) << 3) + (fg << 2);
        float v = acc[mi][ni][r] + bv;
        if (relu) v = fmaxf(v, 0.f);
        store_out(&C[row * N + col], v);
      }
    }
}

// ---------------------------------------------------------------------------
// Causal depthwise conv(4) + SiLU -> U(bf16); also silu(z) -> G(bf16)
// XZ is bf16 now. block=256 (d), grid=32768 (bl)
// ---------------------------------------------------------------------------
__global__ __launch_bounds__(256) void conv_silu_kernel(
    const bf16* __restrict__ XZ, const float* __restrict__ conv_w,
    const float* __restrict__ conv_b, bf16* __restrict__ U,
    bf16* __restrict__ G) {
  int d = threadIdx.x;
  long bl = blockIdx.x;
  int t = (int)(bl & (SEQ - 1));
  float w0 = conv_w[d * 4 + 0], w1 = conv_w[d * 4 + 1];
  float w2 = conv_w[d * 4 + 2], w3 = conv_w[d * 4 + 3];
  const bf16* xp = XZ + bl * 512 + d;
  float acc = conv_b[d] + w3 * bf2f(xp[0]);
  if (t >= 1) acc += w2 * bf2f(xp[-512]);
  if (t >= 2) acc += w1 * bf2f(xp[-1024]);
  if (t >= 3) acc += w0 * bf2f(xp[-1536]);
  float su = acc / (1.f + __expf(-acc));
  float z = bf2f(xp[256]);
  float g = z / (1.f + __expf(-z));
  U[bl * 256 + d] = f2bf(su);
  G[bl * 256 + d] = f2bf(g);
}

// ---------------------------------------------------------------------------
// dt = softplus(dt_r @ W_dt + b_dt) -> bf16. block=256 (d), grid=32768 (bl)
// ---------------------------------------------------------------------------
__global__ __launch_bounds__(256) void dtprep_kernel(
    const float* __restrict__ DBC, const float* __restrict__ W_dt,
    const float* __restrict__ b_dt, bf16* __restrict__ DTo) {
  __shared__ float r8[8];
  int d = threadIdx.x;
  long bl = blockIdx.x;
  if (d < 8) r8[d] = DBC[bl * 40 + d];
  __syncthreads();
  float acc = b_dt[d];
  #pragma unroll
  for (int r = 0; r < 8; ++r) acc = fmaf(r8[r], W_dt[r * 256 + d], acc);
  float dt = (acc > 15.f) ? acc : log1pf(__expf(acc));
  DTo[bl * 256 + d] = f2bf(dt);
}

// ---------------------------------------------------------------------------
// Chunked scan pass 1: per (b,d,s,chunk) run from h=0, record P=prod(a), S=h.
// block: 256 thr = 16 d x 16 s. grid = (16 dgroup, 16 chunk, 8 b)
// ---------------------------------------------------------------------------
__global__ __launch_bounds__(256) void scan_pass1_kernel(
    const bf16* __restrict__ DT, const bf16* __restrict__ U,
    const float* __restrict__ DBC, const float* __restrict__ A_log,
    float* __restrict__ CSP, float* __restrict__ CSS) {
  int s = threadIdx.x & 15, dd = threadIdx.x >> 4;
  int d = blockIdx.x * 16 + dd;
  int c = blockIdx.y, b = blockIdx.z;
  float A2 = -__expf(A_log[d * 16 + s]) * 1.44269504088896f;
  long t0 = (long)b * SEQ + (long)c * CHUNK;
  const bf16* dtp = DT + t0 * 256 + d;
  const bf16* up = U + t0 * 256 + d;
  const float* bp = DBC + t0 * 40 + 8 + s;
  float h = 0.f, P = 1.f;
  #pragma unroll 4
  for (int t = 0; t < CHUNK; ++t) {
    float dt = bf2f(*dtp);
    float u = bf2f(*up);
    float Bv = *bp;
    float a = __builtin_amdgcn_exp2f(dt * A2);
    h = fmaf(a, h, dt * u * Bv);
    P *= a;
    dtp += 256; up += 256; bp += 40;
  }
  int idx = (b * 16 + c) * 4096 + d * 16 + s;
  CSP[idx] = P;
  CSS[idx] = h;
}

// ---------------------------------------------------------------------------
// Chain chunk states: hinit[c] = S[c-1] + P[c-1]*hinit[c-1]. 32768 threads.
// ---------------------------------------------------------------------------
__global__ __launch_bounds__(256) void scan_combine_kernel(
    const float* __restrict__ P, const float* __restrict__ S,
    float* __restrict__ HI) {
  int id = blockIdx.x * 256 + threadIdx.x;  // (b, d*16+s)
  int b = id >> 12, ds = id & 4095;
  float h = 0.f;
  #pragma unroll
  for (int c = 0; c < NCHUNK; ++c) {
    int idx = ((b * 16 + c) << 12) + ds;
    HI[idx] = h;
    h = S[idx] + P[idx] * h;
  }
}

// ---------------------------------------------------------------------------
// Chunked scan pass 2: replay with h_init, reduce y over s, fuse skip+gate.
// Y (bf16) = (y + u*D_skip) * silu(z)
// ---------------------------------------------------------------------------
__global__ __launch_bounds__(256) void scan_pass2_kernel(
    const bf16* __restrict__ DT, const bf16* __restrict__ U,
    const float* __restrict__ DBC, const bf16* __restrict__ G,
    const float* __restrict__ HI, const float* __restrict__ A_log,
    const float* __restrict__ D_skip, bf16* __restrict__ Y) {
  int s = threadIdx.x & 15, dd = threadIdx.x >> 4;
  int d = blockIdx.x * 16 + dd;
  int c = blockIdx.y, b = blockIdx.z;
  float A2 = -__expf(A_log[d * 16 + s]) * 1.44269504088896f;
  float Dv = D_skip[d];
  long t0 = (long)b * SEQ + (long)c * CHUNK;
  const bf16* dtp = DT + t0 * 256 + d;
  const bf16* up = U + t0 * 256 + d;
  const bf16* gp = G + t0 * 256 + d;
  const float* bp = DBC + t0 * 40 + 8 + s;
  bf16* yp = Y + t0 * 256 + d;
  int idx = (b * 16 + c) * 4096 + d * 16 + s;
  float h = HI[idx];
  #pragma unroll 4
  for (int t = 0; t < CHUNK; ++t) {
    float dt = bf2f(*dtp);
    float u = bf2f(*up);
    float Bv = *bp;
    float Cv = bp[16];
    float a = __builtin_amdgcn_exp2f(dt * A2);
    h = fmaf(a, h, dt * u * Bv);
    float p = h * Cv;
    p += __shfl_xor(p, 8, 16);
    p += __shfl_xor(p, 4, 16);
    p += __shfl_xor(p, 2, 16);
    p += __shfl_xor(p, 1, 16);
    if (s == 0) {
      float g = bf2f(*gp);
      *yp = f2bf((p + u * Dv) * g);
    }
    dtp += 256; up += 256; gp += 256; bp += 40; yp += 256;
  }
}

// ---------------------------------------------------------------------------
// kernel_launch
// ---------------------------------------------------------------------------
extern "C" void kernel_launch(void* const* d_in, const int* in_sizes, int n_in,
                              void* d_out, int out_size, void* d_ws,
                              size_t ws_size, hipStream_t stream) {
  const int*   tokens  = (const int*)d_in[0];
  const float* emb     = (const float*)d_in[1];
  const float* ln_w    = (const float*)d_in[2];
  const float* ln_b    = (const float*)d_in[3];
  const float* W_in    = (const float*)d_in[4];
  const float* conv_w  = (const float*)d_in[5];
  const float* conv_b  = (const float*)d_in[6];
  const float* W_xproj = (const float*)d_in[7];
  const float* W_dt    = (const float*)d_in[8];
  const float* b_dt    = (const float*)d_in[9];
  const float* A_log   = (const float*)d_in[10];
  const float* D_skip  = (const float*)d_in[11];
  const float* W_out   = (const float*)d_in[12];
  const float* W1      = (const float*)d_in[13];
  const float* b1      = (const float*)d_in[14];
  const float* W2      = (const float*)d_in[15];
  const float* b2      = (const float*)d_in[16];

  char* ws = (char*)d_ws;
  bf16*  XZ   = (bf16*) (ws + 16777216);       // 32768*512 bf16  33.6MB
  bf16*  XN   = (bf16*) (ws + 83886080);       // 32768*128 bf16   8.4MB (= XBF)
  bf16*  U    = (bf16*) (ws + 92274688);       // 32768*256 bf16  16.8MB
  bf16*  G    = (bf16*) (ws + 109051904);      // 32768*256 bf16  16.8MB
  float* DBC  = (float*)(ws + 125829120);      // 32768*40  f32    5.2MB
  bf16*  DT   = (bf16*) (ws + 131072000);      // 32768*256 bf16  16.8MB
  bf16*  Y    = (bf16*) (ws + 164626432);      // 32768*256 bf16  16.8MB
  float* CSP  = (float*)(ws + 181403648);      // 524288 f32       2.1MB
  float* CSS  = (float*)(ws + 183500800);      // 524288 f32       2.1MB
  float* HI   = (float*)(ws + 185597952);      // 524288 f32       2.1MB
  bf16*  Wt   = (bf16*) (ws + 187695104);      // 2686976 bf16     5.4MB
  bf16*  H    = (bf16*) XZ;                    // overlay: 32768*512 bf16 (XZ dead)
  bf16*  XBF  = XN;                            // layer-3 output, no LN

  bf16* Wt_in  = Wt;              // 4 x [512][128]
  bf16* Wt_xp  = Wt + 262144;     // 4 x [128][256] (rows 40..127 zero)
  bf16* Wt_out = Wt + 393216;     // 4 x [128][256]
  bf16* Wt_1   = Wt + 524288;     // [512][128]
  bf16* Wt_2   = Wt + 589824;     // [4096][512]

  convw_kernel<<<2048, 256, 0, stream>>>(W_in, W_xproj, W_out, W1, W2, Wt);
  // layer-0 input: fused embed+LN
  embln_kernel<<<8192, 256, 0, stream>>>(tokens, emb, ln_w, ln_b, XN);

  for (int i = 0; i < N_LAYERS; ++i) {
    // M=32768 (128 tiles) x N=512 (2 tiles) -> 256 blocks; bf16 out
    gemm256_kernel<bf16><<<256, 512, 0, stream>>>(
        XN, Wt_in + i * 65536, XZ, nullptr, 128, 512, 2, 0);
    conv_silu_kernel<<<32768, 256, 0, stream>>>(
        XZ, conv_w + i * 1024, conv_b + i * 256, U, G);
    gemm_kernel<float, 0><<<dim3(256, 1), 256, 0, stream>>>(
        U, Wt_xp + i * 32768, DBC, nullptr, nullptr, 256, 40);
    dtprep_kernel<<<32768, 256, 0, stream>>>(
        DBC, W_dt + i * 2048, b_dt + i * 256, DT);
    scan_pass1_kernel<<<dim3(16, 16, 8), 256, 0, stream>>>(
        DT, U, DBC, A_log + i * 4096, CSP, CSS);
    scan_combine_kernel<<<128, 256, 0, stream>>>(CSP, CSS, HI);
    scan_pass2_kernel<<<dim3(16, 16, 8), 256, 0, stream>>>(
        DT, U, DBC, G, HI, A_log + i * 4096, D_skip + i * 256, Y);
    if (i < N_LAYERS - 1) {
      // W_out + fused LayerNorm of NEXT layer -> XN bf16
      gemm_kernel<bf16, 2><<<dim3(256, 1), 256, 0, stream>>>(
          Y, Wt_out + i * 32768, XN, ln_w + (i + 1) * 128,
          ln_b + (i + 1) * 128, 256, 128);
    } else {
      gemm_kernel<bf16, 0><<<dim3(256, 1), 256, 0, stream>>>(
          Y, Wt_out + i * 32768, XBF, nullptr, nullptr, 256, 128);
    }
  }

  // MLP head: H = relu(XBF @ W1 + b1) in bf16, then out = H @ W2 + b2 (fp32)
  gemm256_kernel<bf16><<<256, 512, 0, stream>>>(
      XBF, Wt_1, H, b1, 128, 512, 2, 1);
  gemm256_kernel<float><<<2048, 512, 0, stream>>>(
      H, Wt_2, (float*)d_out, b2, 512, 4096, 16, 0);
}